// Round 19
// baseline (271.975 us; speedup 1.0000x reference)
//
#include <hip/hip_runtime.h>
#include <hip/hip_bf16.h>

// Problem constants (match reference)
#define NN 20000
#define EE 640000
#define DD 256
#define GG 64
#define ETOT (EE + NN)   // edges + self loops = 660000
#define BN_EPS 1e-5f

// hist partitioning: partition = blockIdx%8 (XCD round-robin), chunk = blockIdx/16
#define NPART 8
#define PBLK  128                 // chunks
#define CE    (EE / PBLK)         // 5000 edges per chunk
#define PRNG  (NN / NPART)        // 2500 nodes per partition

#define GBM 64
#define GBN 64
#define GBK 64
#define NROWB 313                 // ceil(NN/GBM)
#define NCOLB 4                   // DD/GBN
#define NGEMMB (NROWB * NCOLB)    // 1252 blocks
// scatter-in-epilogue partitioning: blocks 0..623 -> chunk=lid>>3, part=lid&7
#define SCHUNKS 78
#define SCSZ 8206                 // 78*8206 >= EE

typedef short s16x8 __attribute__((ext_vector_type(8)));
typedef float f32x4 __attribute__((ext_vector_type(4)));
typedef int   i32x2 __attribute__((ext_vector_type(2)));
typedef int   i32x4 __attribute__((ext_vector_type(4)));

__device__ __forceinline__ unsigned short f2bf_hi(float x) {
    unsigned u = __float_as_uint(x);
    unsigned r = (u + 0x7FFFu + ((u >> 16) & 1u)) >> 16;   // RNE
    return (unsigned short)r;
}
__device__ __forceinline__ float bf2f(unsigned short h) {
    return __uint_as_float(((unsigned)h) << 16);
}

// async 16B global->LDS DMA (wave-uniform LDS base + lane*16 linear dest)
__device__ __forceinline__ void gload_lds16(const void* g, void* l) {
    __builtin_amdgcn_global_load_lds(
        (const __attribute__((address_space(1))) void*)g,
        (__attribute__((address_space(3))) void*)l,
        16, 0, 0);
}

// 8 bf16 features from one 16B load at (hbF + byte_off), u32-pair unpack
__device__ __forceinline__ void fma8o(const char* __restrict__ hbF, int boff,
                                      float a, float* acc) {
    i32x4 hv = *(const i32x4*)(hbF + boff);
    #pragma unroll
    for (int k = 0; k < 4; ++k) {
        unsigned u = (unsigned)hv[k];
        acc[2 * k]     += a * __uint_as_float(u << 16);
        acc[2 * k + 1] += a * __uint_as_float(u & 0xFFFF0000u);
    }
}

// ---------------------------------------------------------------------------
// Merged launch A: hist (1024 blocks, partition=b%8) || convB (512) || prep (1)
// ---------------------------------------------------------------------------
__global__ __launch_bounds__(256) void prep_hist_conv_kernel(
        const int* __restrict__ batch, int* __restrict__ start, float* __restrict__ cntf,
        const int* __restrict__ ei, int* __restrict__ counts,
        const float* __restrict__ W1, const float* __restrict__ W2,
        short* __restrict__ BhT1, short* __restrict__ BlT1,
        short* __restrict__ BhT2, short* __restrict__ BlT2) {
    int b = blockIdx.x;
    int r = b & 15, G = b >> 4;
    if (r < 8) {                       // hist
        int lo = (b & 7) * PRNG;
        int e0 = G * CE;
        for (int i = e0 + threadIdx.x; i < e0 + CE; i += 256) {
            int d = ei[EE + i];
            if ((unsigned)(d - lo) < (unsigned)PRNG) atomicAdd(&counts[d], 1);
        }
        return;
    }
    int idx = G * 8 + (r - 8);
    if (idx < 512) {                   // convB
        int n = idx & 255, which = idx >> 8;
        int k = threadIdx.x;
        const float* B = which ? W2 : W1;
        short* Bh = which ? BhT2 : BhT1;
        short* Bl = which ? BlT2 : BlT1;
        float x = B[k * DD + n];
        unsigned short hbv = f2bf_hi(x);
        Bh[n * DD + k] = (short)hbv;
        Bl[n * DD + k] = (short)f2bf_hi(x - bf2f(hbv));
    } else if (idx == 512) {           // prep
        int g = threadIdx.x;
        if (g <= GG) {
            if (g == GG) start[GG] = NN;
            else {
                int lo = 0, hi = NN;
                while (lo < hi) { int mid = (lo + hi) >> 1; if (batch[mid] < g) lo = mid + 1; else hi = mid; }
                start[g] = lo;
            }
        }
        __syncthreads();
        if (g < GG) cntf[g] = (float)(start[g + 1] - start[g]);
    }
}

// ---------------------------------------------------------------------------
// Scan: counts+1 (self-loop) -> exclusive offsets + cursor
// ---------------------------------------------------------------------------
#define SCHUNK 20
__global__ __launch_bounds__(1024) void scan_kernel(const int* __restrict__ counts,
                                                    int* __restrict__ offsets,
                                                    int* __restrict__ cursor) {
    __shared__ int wsums[16];
    int t = threadIdx.x, lane = t & 63, wid = t >> 6;
    int base = t * SCHUNK;
    int loc[SCHUNK];
    int sum = 0;
    #pragma unroll
    for (int i = 0; i < SCHUNK; ++i) {
        int idx = base + i;
        int v = (idx < NN) ? (counts[idx] + 1) : 0;
        loc[i] = sum; sum += v;
    }
    int x = sum;
    #pragma unroll
    for (int o = 1; o < 64; o <<= 1) { int tv = __shfl_up(x, o, 64); if (lane >= o) x += tv; }
    if (lane == 63) wsums[wid] = x;
    __syncthreads();
    if (wid == 0) {
        int wv = (lane < 16) ? wsums[lane] : 0;
        #pragma unroll
        for (int o = 1; o < 16; o <<= 1) { int tv = __shfl_up(wv, o, 64); if (lane >= o) wv += tv; }
        if (lane < 16) wsums[lane] = wv;
    }
    __syncthreads();
    int tbase = (wid ? wsums[wid - 1] : 0) + x - sum;
    #pragma unroll
    for (int i = 0; i < SCHUNK; ++i) {
        int idx = base + i;
        if (idx < NN) { int e = tbase + loc[i]; offsets[idx] = e; cursor[idx] = e; }
    }
    if (t == 0) offsets[NN] = wsums[15];
}

// ---------------------------------------------------------------------------
// MFMA GEMM: h = A[M x 256] @ W[256 x 256], split-bf16 3-pass.
// 64x64 tile (32KB LDS -> 5 blocks/CU, 20 waves/CU for latency hiding).
// B staged via async global_load_lds (pre-swizzled source, linear dest).
// Layer 1 (SCAT) appends an XCD-partitioned scatter chunk (part = lid&7).
// ---------------------------------------------------------------------------
template<bool SCAT>
__global__ __launch_bounds__(256) void gemm_kernel(
        const float* __restrict__ A,
        const short* __restrict__ BhT, const short* __restrict__ BlT,
        const float* __restrict__ a_src, const float* __restrict__ a_dst,
        short* __restrict__ hb, float* __restrict__ asp, float* __restrict__ adp, int M,
        const int* __restrict__ ei, int* __restrict__ cursor, int* __restrict__ csr_src) {
    __shared__ short As_h[GBM * GBK];
    __shared__ short As_l[GBM * GBK];
    __shared__ short Bs_h[GBN * GBK];
    __shared__ short Bs_l[GBN * GBK];
    int tid = threadIdx.x;
    int lid = blockIdx.x;
    int gx = lid & 3, gy = lid >> 2;
    int row0 = gy * GBM;
    int col0 = gx * GBN;
    int w = tid >> 6, lane = tid & 63;
    int wr = w >> 1, wc = w & 1;   // wr: 32-row half, wc: 32-col half

    f32x4 acc[2][2];
    #pragma unroll
    for (int m = 0; m < 2; ++m)
        #pragma unroll
        for (int n = 0; n < 2; ++n)
            acc[m][n] = (f32x4){0.f, 0.f, 0.f, 0.f};

    int srow = tid >> 3;     // 0..31
    int sslot = tid & 7;     // 0..7

    for (int k0 = 0; k0 < DD; k0 += GBK) {
        __syncthreads();
        // ---- B tile: async DMA, pre-swizzled global source, linear LDS ----
        #pragma unroll
        for (int p = 0; p < 2; ++p) {
            int r = p * 32 + srow;
            int sswz = sslot ^ (r & 7);
            const short* bhp = BhT + (size_t)(col0 + r) * DD + k0 + sswz * 8;
            const short* blp = BlT + (size_t)(col0 + r) * DD + k0 + sswz * 8;
            gload_lds16(bhp, (char*)Bs_h + p * 4096 + w * 1024);
            gload_lds16(blp, (char*)Bs_l + p * 4096 + w * 1024);
        }
        // ---- A tile: load fp32, convert to bf16 hi/lo, swizzled ds_write ----
        #pragma unroll
        for (int p = 0; p < 2; ++p) {
            int r = p * 32 + srow;
            int gr = row0 + r;
            float xv[8];
            if (gr < M) {
                const float4* ap = (const float4*)(A + (size_t)gr * DD + k0 + sslot * 8);
                float4 a0 = ap[0], a1 = ap[1];
                xv[0] = a0.x; xv[1] = a0.y; xv[2] = a0.z; xv[3] = a0.w;
                xv[4] = a1.x; xv[5] = a1.y; xv[6] = a1.z; xv[7] = a1.w;
            } else {
                #pragma unroll
                for (int i = 0; i < 8; ++i) xv[i] = 0.f;
            }
            s16x8 hv, lv;
            #pragma unroll
            for (int i = 0; i < 8; ++i) {
                unsigned short hbb = f2bf_hi(xv[i]);
                hv[i] = (short)hbb;
                lv[i] = (short)f2bf_hi(xv[i] - bf2f(hbb));
            }
            int byte = r * 128 + ((sslot ^ (r & 7)) << 4);
            *(s16x8*)((char*)As_h + byte) = hv;
            *(s16x8*)((char*)As_l + byte) = lv;
        }
        __syncthreads();

        #pragma unroll
        for (int ks = 0; ks < 2; ++ks) {
            s16x8 ah[2], al[2], bh[2], bl[2];
            int g = ks * 4 + (lane >> 4);
            #pragma unroll
            for (int m = 0; m < 2; ++m) {
                int r = wr * 32 + m * 16 + (lane & 15);
                int byte = r * 128 + ((g ^ (r & 7)) << 4);
                ah[m] = *(const s16x8*)((char*)As_h + byte);
                al[m] = *(const s16x8*)((char*)As_l + byte);
            }
            #pragma unroll
            for (int n = 0; n < 2; ++n) {
                int c = wc * 32 + n * 16 + (lane & 15);
                int byte = c * 128 + ((g ^ (c & 7)) << 4);
                bh[n] = *(const s16x8*)((char*)Bs_h + byte);
                bl[n] = *(const s16x8*)((char*)Bs_l + byte);
            }
            #pragma unroll
            for (int m = 0; m < 2; ++m)
                #pragma unroll
                for (int n = 0; n < 2; ++n) {
                    acc[m][n] = __builtin_amdgcn_mfma_f32_16x16x32_bf16(ah[m], bh[n], acc[m][n], 0, 0, 0);
                    acc[m][n] = __builtin_amdgcn_mfma_f32_16x16x32_bf16(ah[m], bl[n], acc[m][n], 0, 0, 0);
                    acc[m][n] = __builtin_amdgcn_mfma_f32_16x16x32_bf16(al[m], bh[n], acc[m][n], 0, 0, 0);
                }
        }
    }

    // fused matvec partials (exact fp32 accumulators), plain stores
    // slab index = gx*2 + wc  (8 slabs total)
    float vsrc[2], vdst[2];
    #pragma unroll
    for (int n = 0; n < 2; ++n) {
        int cg = col0 + wc * 32 + n * 16 + (lane & 15);
        vsrc[n] = a_src[cg];
        vdst[n] = a_dst[cg];
    }
    #pragma unroll
    for (int m = 0; m < 2; ++m) {
        #pragma unroll
        for (int j = 0; j < 4; ++j) {
            float ps = 0.f, pd = 0.f;
            #pragma unroll
            for (int n = 0; n < 2; ++n) {
                float c = acc[m][n][j];
                ps += c * vsrc[n];
                pd += c * vdst[n];
            }
            #pragma unroll
            for (int o = 1; o < 16; o <<= 1) {
                ps += __shfl_xor(ps, o, 64);
                pd += __shfl_xor(pd, o, 64);
            }
            if ((lane & 15) == 0) {
                int rg = row0 + wr * 32 + m * 16 + ((lane >> 4) << 2) + j;
                if (rg < M) {
                    asp[(size_t)(gx * 2 + wc) * NN + rg] = ps;
                    adp[(size_t)(gx * 2 + wc) * NN + rg] = pd;
                }
            }
        }
    }

    // bf16 h output
    #pragma unroll
    for (int m = 0; m < 2; ++m) {
        int rbase = row0 + wr * 32 + m * 16 + ((lane >> 4) << 2);
        #pragma unroll
        for (int n = 0; n < 2; ++n) {
            int cg = col0 + wc * 32 + n * 16 + (lane & 15);
            #pragma unroll
            for (int j = 0; j < 4; ++j) {
                int rg = rbase + j;
                if (rg < M) hb[(size_t)rg * DD + cg] = (short)f2bf_hi(acc[m][n][j]);
            }
        }
    }

    // XCD-partitioned scatter epilogue (layer 1 only)
    if (SCAT && lid < SCHUNKS * NPART) {
        int part = lid & 7;
        int lo = part * PRNG;
        int e0 = (lid >> 3) * SCSZ;
        int e1 = min(e0 + SCSZ, EE);
        for (int i = e0 + tid; i < e1; i += 256) {
            int d = ei[EE + i];
            if ((unsigned)(d - lo) < (unsigned)PRNG) {
                int pos = atomicAdd(&cursor[d], 1);
                csr_src[pos] = ei[i];
            }
        }
    }
}

// ---------------------------------------------------------------------------
// Collapse the 8 partial slabs into as_/ad_; self-loop into last CSR slot.
// ---------------------------------------------------------------------------
__global__ void reduce_kernel(const float* __restrict__ asp, const float* __restrict__ adp,
                              const int* __restrict__ offsets,
                              float* __restrict__ as_, float* __restrict__ ad_,
                              int* __restrict__ csr_src) {
    int i = blockIdx.x * blockDim.x + threadIdx.x;
    if (i < NN) {
        float s = 0.f, d = 0.f;
        #pragma unroll
        for (int k = 0; k < 8; ++k) {
            s += asp[(size_t)k * NN + i];
            d += adp[(size_t)k * NN + i];
        }
        as_[i] = s;
        ad_[i] = d;
        csr_src[offsets[i + 1] - 1] = i;   // self-loop
    }
}

// ---------------------------------------------------------------------------
// Alpha precompute: wave per node; fast path deg<=64. Writes packed
// {src_byte_offset (src*512), alpha} so the aggregate needs no multiply.
// ---------------------------------------------------------------------------
__global__ __launch_bounds__(256) void alpha_kernel(const int* __restrict__ csr_src,
                                                    const int* __restrict__ offsets,
                                                    const float* __restrict__ as_,
                                                    const float* __restrict__ ad_,
                                                    int2* __restrict__ pairs) {
    int tid = threadIdx.x;
    int w = tid >> 6, lane = tid & 63;
    int node = blockIdx.x * 4 + w;
    int off = offsets[node];
    int deg = offsets[node + 1] - off;
    float adn = ad_[node];

    if (deg <= 64) {
        int si = 0; float e = -INFINITY;
        if (lane < deg) {
            si = csr_src[off + lane];
            float t = as_[si] + adn;
            e = (t > 0.f) ? t : 0.2f * t;
        }
        float m = e;
        #pragma unroll
        for (int o = 32; o > 0; o >>= 1) m = fmaxf(m, __shfl_xor(m, o, 64));
        float ex = (lane < deg) ? expf(e - m) : 0.f;
        float s = ex;
        #pragma unroll
        for (int o = 32; o > 0; o >>= 1) s += __shfl_xor(s, o, 64);
        if (lane < deg) {
            int2 p; p.x = si << 9; p.y = __float_as_int(ex / s);
            pairs[off + lane] = p;
        }
        return;
    }

    float m = -INFINITY, s = 0.f;
    for (int cs = 0; cs < deg; cs += 64) {
        int cl = min(64, deg - cs);
        float e = -INFINITY;
        if (lane < cl) {
            int si = csr_src[off + cs + lane];
            float t = as_[si] + adn;
            e = (t > 0.f) ? t : 0.2f * t;
        }
        float cm = e;
        #pragma unroll
        for (int o = 32; o > 0; o >>= 1) cm = fmaxf(cm, __shfl_xor(cm, o, 64));
        float newm = fmaxf(m, cm);
        float ex = (lane < cl) ? expf(e - newm) : 0.f;
        float csum = ex;
        #pragma unroll
        for (int o = 32; o > 0; o >>= 1) csum += __shfl_xor(csum, o, 64);
        s = s * expf(m - newm) + csum;
        m = newm;
    }
    float inv = 1.f / s;
    for (int cs = 0; cs < deg; cs += 64) {
        int cl = min(64, deg - cs);
        if (lane < cl) {
            int si = csr_src[off + cs + lane];
            float t = as_[si] + adn;
            float e = (t > 0.f) ? t : 0.2f * t;
            int2 p; p.x = si << 9; p.y = __float_as_int(expf(e - m) * inv);
            pairs[off + cs + lane] = p;
        }
    }
}

// ---------------------------------------------------------------------------
// Aggregation v4 + byte-offset pairs (round-12 proven). Wave per
// (node, 64-feature slice); 8 edge groups x 8 lanes x 16B; pairs prefetched
// one iteration ahead. slice=blockIdx%4 pins each XCD's L2 to one h-slice.
// ---------------------------------------------------------------------------
__global__ __launch_bounds__(256) void aggregate_kernel(const short* __restrict__ hb,
                                                        const int2* __restrict__ pairs,
                                                        const int* __restrict__ offsets,
                                                        const float* __restrict__ bias,
                                                        float* __restrict__ out) {
    int tid = threadIdx.x;
    int w = tid >> 6, lane = tid & 63;
    int b = blockIdx.x;
    int sl = b & 3;
    int node = ((b >> 2) << 2) + w;
    int eg = lane >> 3;          // edge group 0..7
    int fl = lane & 7;           // feature octet
    int f0 = sl * 64 + fl * 8;
    const char* hbF = (const char*)hb + f0 * 2;
    int off = offsets[node];
    int deg = offsets[node + 1] - off;
    const i32x2* pp = (const i32x2*)pairs + off;

    float accA[8], accB[8];
    #pragma unroll
    for (int k = 0; k < 8; ++k) { accA[k] = 0.f; accB[k] = 0.f; }

    int j = 0;
    i32x2 qA, qB;
    if (deg >= 16) { qA = pp[eg]; qB = pp[8 + eg]; }
    for (; j + 32 <= deg; j += 16) {
        i32x2 nA = pp[j + 16 + eg];                  // prefetch next iter
        i32x2 nB = pp[j + 24 + eg];
        fma8o(hbF, qA[0], __int_as_float(qA[1]), accA);
        fma8o(hbF, qB[0], __int_as_float(qB[1]), accB);
        qA = nA; qB = nB;
    }
    if (j + 16 <= deg) {                             // last full iter (pairs in regs)
        fma8o(hbF, qA[0], __int_as_float(qA[1]), accA);
        fma8o(hbF, qB[0], __int_as_float(qB[1]), accB);
        j += 16;
    }
    {   // tail: up to 15 edges, two guarded per-group singles
        if (j + eg < deg) {
            i32x2 p = pp[j + eg];
            fma8o(hbF, p[0], __int_as_float(p[1]), accA);
        }
        if (j + 8 + eg < deg) {
            i32x2 p = pp[j + 8 + eg];
            fma8o(hbF, p[0], __int_as_float(p[1]), accB);
        }
    }

    // merge the 8 edge groups
    f32x4 r0, r1;
    #pragma unroll
    for (int k = 0; k < 8; ++k) {
        float v = accA[k] + accB[k];
        v += __shfl_xor(v, 8, 64);
        v += __shfl_xor(v, 16, 64);
        v += __shfl_xor(v, 32, 64);
        if (k < 4) r0[k] = v; else r1[k - 4] = v;
    }
    if (eg == 0) {
        const f32x4 b0 = *(const f32x4*)(bias + f0);
        const f32x4 b1 = *(const f32x4*)(bias + f0 + 4);
        #pragma unroll
        for (int k = 0; k < 4; ++k) {
            float v0 = r0[k] + b0[k];
            float v1 = r1[k] + b1[k];
            r0[k] = (v0 > 0.f) ? v0 : 0.01f * v0;
            r1[k] = (v1 > 0.f) ? v1 : 0.01f * v1;
        }
        __builtin_nontemporal_store(r0, (f32x4*)(out + (size_t)node * DD + f0));
        __builtin_nontemporal_store(r1, (f32x4*)(out + (size_t)node * DD + f0 + 4));
    }
}

// ---------------------------------------------------------------------------
// Pool + final (BN folded into final)
// ---------------------------------------------------------------------------
#define PSLICE 8
__global__ __launch_bounds__(256) void pool_kernel(const float* __restrict__ h,
                                                   const int* __restrict__ start,
                                                   float* __restrict__ pool) {
    int g = blockIdx.x >> 3, sl = blockIdx.x & (PSLICE - 1);
    int f = threadIdx.x;
    int s0 = start[g], s1 = start[g + 1];
    float acc = 0.f;
    for (int nd = s0 + sl; nd < s1; nd += PSLICE)
        acc += h[(size_t)nd * DD + f];
    if (acc != 0.f || sl == 0) atomicAdd(&pool[g * DD + f], acc);
}

__global__ __launch_bounds__(256) void final_kernel(const float* __restrict__ pool,
                                                    const float* __restrict__ cnt,
                                                    const float* __restrict__ gam,
                                                    const float* __restrict__ bet,
                                                    const float* __restrict__ mean,
                                                    const float* __restrict__ var,
                                                    const float* __restrict__ Wl,
                                                    const float* __restrict__ bl,
                                                    float* __restrict__ out) {
    __shared__ float p_sh[DD];
    int g = blockIdx.x, j = threadIdx.x;
    float cn = cnt[g];
    float scale = gam[j] * rsqrtf(var[j] + BN_EPS);
    p_sh[j] = (cn > 0.f) ? (pool[g * DD + j] / cn - mean[j]) * scale + bet[j] : 0.f;
    __syncthreads();
    float acc = 0.f;
    for (int fi = 0; fi < DD; ++fi)
        acc += p_sh[fi] * Wl[j * DD + fi];
    out[g * DD + j] = acc + bl[j];
}

// ---------------------------------------------------------------------------
extern "C" void kernel_launch(void* const* d_in, const int* in_sizes, int n_in,
                              void* d_out, int out_size, void* d_ws, size_t ws_size,
                              hipStream_t stream) {
    const float* x       = (const float*)d_in[0];
    const int*   ei      = (const int*)d_in[1];
    const int*   batch   = (const int*)d_in[2];
    const float* W1      = (const float*)d_in[3];
    const float* a1_src  = (const float*)d_in[4];
    const float* a1_dst  = (const float*)d_in[5];
    const float* b1      = (const float*)d_in[6];
    const float* W2      = (const float*)d_in[7];
    const float* a2_src  = (const float*)d_in[8];
    const float* a2_dst  = (const float*)d_in[9];
    const float* b2      = (const float*)d_in[10];
    const float* bn_g    = (const float*)d_in[11];
    const float* bn_b    = (const float*)d_in[12];
    const float* bn_m    = (const float*)d_in[13];
    const float* bn_v    = (const float*)d_in[14];
    const float* Wl      = (const float*)d_in[15];
    const float* bl      = (const float*)d_in[16];
    float* out = (float*)d_out;

    char* ws = (char*)d_ws;
    size_t o = 0;
    auto take = [&](size_t bytes) { char* p = ws + o; o += (bytes + 255) & ~(size_t)255; return p; };
    int*   counts  = (int*)  take(NN * 4);
    int*   offsets = (int*)  take((NN + 1) * 4);
    int*   cursor  = (int*)  take(NN * 4);
    int*   csr_src = (int*)  take((size_t)ETOT * 4);
    int2*  pairs   = (int2*) take((size_t)ETOT * 8);
    float* asp     = (float*)take((size_t)8 * NN * 4);
    float* adp     = (float*)take((size_t)8 * NN * 4);
    float* as_     = (float*)take(NN * 4);
    float* ad_     = (float*)take(NN * 4);
    short* hb      = (short*)take((size_t)NN * DD * 2);
    float* bufB    = (float*)take((size_t)NN * DD * 4);
    float* pool    = (float*)take(GG * DD * 4);
    float* cnt     = (float*)take(GG * 4);
    int*   start   = (int*)  take((GG + 1) * 4);
    short* BhT1    = (short*)take((size_t)DD * DD * 2);
    short* BlT1    = (short*)take((size_t)DD * DD * 2);
    short* BhT2    = (short*)take((size_t)DD * DD * 2);
    short* BlT2    = (short*)take((size_t)DD * DD * 2);
    (void)ws_size; (void)in_sizes; (void)n_in; (void)out_size;

    hipMemsetAsync(counts, 0, NN * 4, stream);
    hipMemsetAsync(pool, 0, GG * DD * 4, stream);

    // launch A: hist || convB || prep
    prep_hist_conv_kernel<<<2048, 256, 0, stream>>>(batch, start, cnt, ei, counts,
                                                    W1, W2, BhT1, BlT1, BhT2, BlT2);
    scan_kernel<<<1, 1024, 0, stream>>>(counts, offsets, cursor);

    // ---- layer 1 (GEMM + XCD-partitioned scatter epilogue) ----
    gemm_kernel<true><<<NGEMMB, 256, 0, stream>>>(x, BhT1, BlT1, a1_src, a1_dst,
                                                  hb, asp, adp, NN, ei, cursor, csr_src);
    reduce_kernel<<<(NN + 255) / 256, 256, 0, stream>>>(asp, adp, offsets, as_, ad_, csr_src);
    alpha_kernel<<<NN / 4, 256, 0, stream>>>(csr_src, offsets, as_, ad_, pairs);
    aggregate_kernel<<<NN, 256, 0, stream>>>(hb, pairs, offsets, b1, bufB);

    // ---- layer 2 ----
    gemm_kernel<false><<<NGEMMB, 256, 0, stream>>>(bufB, BhT2, BlT2, a2_src, a2_dst,
                                                   hb, asp, adp, NN, nullptr, nullptr, nullptr);
    reduce_kernel<<<(NN + 255) / 256, 256, 0, stream>>>(asp, adp, offsets, as_, ad_, csr_src);
    alpha_kernel<<<NN / 4, 256, 0, stream>>>(csr_src, offsets, as_, ad_, pairs);
    aggregate_kernel<<<NN, 256, 0, stream>>>(hb, pairs, offsets, b2, bufB);

    // ---- pool + BN + linear ----
    pool_kernel<<<GG * PSLICE, 256, 0, stream>>>(bufB, start, pool);
    final_kernel<<<GG, 256, 0, stream>>>(pool, cnt, bn_g, bn_b, bn_m, bn_v, Wl, bl, out);
}

// Round 20
// 260.323 us; speedup vs baseline: 1.0448x; 1.0448x over previous
//
#include <hip/hip_runtime.h>
#include <hip/hip_bf16.h>

// Problem constants (match reference)
#define NN 20000
#define EE 640000
#define DD 256
#define GG 64
#define ETOT (EE + NN)   // edges + self loops = 660000
#define BN_EPS 1e-5f

// hist partitioning: partition = blockIdx%8 (XCD round-robin), chunk = blockIdx/16
#define NPART 8
#define PBLK  128                 // chunks
#define CE    (EE / PBLK)         // 5000 edges per chunk
#define PRNG  (NN / NPART)        // 2500 nodes per partition

#define GBM 64
#define GBN 128
#define GBK 64
#define NGEMMB 626                // 313 row-blocks x 2 col-blocks
// scatter-in-epilogue partitioning: blocks 0..623 -> chunk=lid>>3, part=lid&7
#define SCHUNKS 78
#define SCSZ 8206                 // 78*8206 >= EE

typedef short s16x8 __attribute__((ext_vector_type(8)));
typedef float f32x4 __attribute__((ext_vector_type(4)));
typedef int   i32x2 __attribute__((ext_vector_type(2)));
typedef int   i32x4 __attribute__((ext_vector_type(4)));

__device__ __forceinline__ unsigned short f2bf_hi(float x) {
    unsigned u = __float_as_uint(x);
    unsigned r = (u + 0x7FFFu + ((u >> 16) & 1u)) >> 16;   // RNE
    return (unsigned short)r;
}
__device__ __forceinline__ float bf2f(unsigned short h) {
    return __uint_as_float(((unsigned)h) << 16);
}

// 8 bf16 features from one 16B load at (hbF + byte_off), u32-pair unpack
__device__ __forceinline__ void fma8o(const char* __restrict__ hbF, int boff,
                                      float a, float* acc) {
    i32x4 hv = *(const i32x4*)(hbF + boff);
    #pragma unroll
    for (int k = 0; k < 4; ++k) {
        unsigned u = (unsigned)hv[k];
        acc[2 * k]     += a * __uint_as_float(u << 16);
        acc[2 * k + 1] += a * __uint_as_float(u & 0xFFFF0000u);
    }
}

// ---------------------------------------------------------------------------
// Merged launch A: hist (1024 blocks, partition=b%8) || convB (512) || prep (1)
// ---------------------------------------------------------------------------
__global__ __launch_bounds__(256) void prep_hist_conv_kernel(
        const int* __restrict__ batch, int* __restrict__ start, float* __restrict__ cntf,
        const int* __restrict__ ei, int* __restrict__ counts,
        const float* __restrict__ W1, const float* __restrict__ W2,
        short* __restrict__ BhT1, short* __restrict__ BlT1,
        short* __restrict__ BhT2, short* __restrict__ BlT2) {
    int b = blockIdx.x;
    int r = b & 15, G = b >> 4;
    if (r < 8) {                       // hist
        int lo = (b & 7) * PRNG;
        int e0 = G * CE;
        for (int i = e0 + threadIdx.x; i < e0 + CE; i += 256) {
            int d = ei[EE + i];
            if ((unsigned)(d - lo) < (unsigned)PRNG) atomicAdd(&counts[d], 1);
        }
        return;
    }
    int idx = G * 8 + (r - 8);
    if (idx < 512) {                   // convB
        int n = idx & 255, which = idx >> 8;
        int k = threadIdx.x;
        const float* B = which ? W2 : W1;
        short* Bh = which ? BhT2 : BhT1;
        short* Bl = which ? BlT2 : BlT1;
        float x = B[k * DD + n];
        unsigned short hbv = f2bf_hi(x);
        Bh[n * DD + k] = (short)hbv;
        Bl[n * DD + k] = (short)f2bf_hi(x - bf2f(hbv));
    } else if (idx == 512) {           // prep
        int g = threadIdx.x;
        if (g <= GG) {
            if (g == GG) start[GG] = NN;
            else {
                int lo = 0, hi = NN;
                while (lo < hi) { int mid = (lo + hi) >> 1; if (batch[mid] < g) lo = mid + 1; else hi = mid; }
                start[g] = lo;
            }
        }
        __syncthreads();
        if (g < GG) cntf[g] = (float)(start[g + 1] - start[g]);
    }
}

// ---------------------------------------------------------------------------
// Scan: counts+1 (self-loop) -> exclusive offsets + cursor
// ---------------------------------------------------------------------------
#define SCHUNK 20
__global__ __launch_bounds__(1024) void scan_kernel(const int* __restrict__ counts,
                                                    int* __restrict__ offsets,
                                                    int* __restrict__ cursor) {
    __shared__ int wsums[16];
    int t = threadIdx.x, lane = t & 63, wid = t >> 6;
    int base = t * SCHUNK;
    int loc[SCHUNK];
    int sum = 0;
    #pragma unroll
    for (int i = 0; i < SCHUNK; ++i) {
        int idx = base + i;
        int v = (idx < NN) ? (counts[idx] + 1) : 0;
        loc[i] = sum; sum += v;
    }
    int x = sum;
    #pragma unroll
    for (int o = 1; o < 64; o <<= 1) { int tv = __shfl_up(x, o, 64); if (lane >= o) x += tv; }
    if (lane == 63) wsums[wid] = x;
    __syncthreads();
    if (wid == 0) {
        int wv = (lane < 16) ? wsums[lane] : 0;
        #pragma unroll
        for (int o = 1; o < 16; o <<= 1) { int tv = __shfl_up(wv, o, 64); if (lane >= o) wv += tv; }
        if (lane < 16) wsums[lane] = wv;
    }
    __syncthreads();
    int tbase = (wid ? wsums[wid - 1] : 0) + x - sum;
    #pragma unroll
    for (int i = 0; i < SCHUNK; ++i) {
        int idx = base + i;
        if (idx < NN) { int e = tbase + loc[i]; offsets[idx] = e; cursor[idx] = e; }
    }
    if (t == 0) offsets[NN] = wsums[15];
}

// ---------------------------------------------------------------------------
// MFMA GEMM: h = A[M x 256] @ W[256 x 256], split-bf16 3-pass, GBM=64.
// 1D grid (lid = blockIdx.x). Layer 1 (SCAT) appends an XCD-PARTITIONED
// scatter chunk: part = lid&7 (XCD round-robin) owns dst range
// [part*2500, +2500) -> each csr/cursor line written by ONE XCD only.
// ---------------------------------------------------------------------------
template<bool SCAT>
__global__ __launch_bounds__(256) void gemm_kernel(
        const float* __restrict__ A,
        const short* __restrict__ BhT, const short* __restrict__ BlT,
        const float* __restrict__ a_src, const float* __restrict__ a_dst,
        short* __restrict__ hb, float* __restrict__ asp, float* __restrict__ adp, int M,
        const int* __restrict__ ei, int* __restrict__ cursor, int* __restrict__ csr_src) {
    __shared__ short As_h[GBM * GBK];
    __shared__ short As_l[GBM * GBK];
    __shared__ short Bs_h[GBN * GBK];
    __shared__ short Bs_l[GBN * GBK];
    int tid = threadIdx.x;
    int lid = blockIdx.x;
    int gx = lid & 1, gy = lid >> 1;
    int row0 = gy * GBM;
    int col0 = gx * GBN;
    int w = tid >> 6, lane = tid & 63;
    int wr = w >> 1, wc = w & 1;

    f32x4 acc[2][4];
    #pragma unroll
    for (int m = 0; m < 2; ++m)
        #pragma unroll
        for (int n = 0; n < 4; ++n)
            acc[m][n] = (f32x4){0.f, 0.f, 0.f, 0.f};

    int srow = tid >> 3;
    int sslot = tid & 7;

    for (int k0 = 0; k0 < DD; k0 += GBK) {
        __syncthreads();
        #pragma unroll
        for (int p = 0; p < 2; ++p) {
            int r = p * 32 + srow;
            int gr = row0 + r;
            float xv[8];
            if (gr < M) {
                const float4* ap = (const float4*)(A + (size_t)gr * DD + k0 + sslot * 8);
                float4 a0 = ap[0], a1 = ap[1];
                xv[0] = a0.x; xv[1] = a0.y; xv[2] = a0.z; xv[3] = a0.w;
                xv[4] = a1.x; xv[5] = a1.y; xv[6] = a1.z; xv[7] = a1.w;
            } else {
                #pragma unroll
                for (int i = 0; i < 8; ++i) xv[i] = 0.f;
            }
            s16x8 hv, lv;
            #pragma unroll
            for (int i = 0; i < 8; ++i) {
                unsigned short hbb = f2bf_hi(xv[i]);
                hv[i] = (short)hbb;
                lv[i] = (short)f2bf_hi(xv[i] - bf2f(hbb));
            }
            int byte = r * 128 + ((sslot ^ (r & 7)) << 4);
            *(s16x8*)((char*)As_h + byte) = hv;
            *(s16x8*)((char*)As_l + byte) = lv;
        }
        #pragma unroll
        for (int p = 0; p < 4; ++p) {
            int r = p * 32 + srow;
            int byte = r * 128 + ((sslot ^ (r & 7)) << 4);
            const short* bhp = BhT + (size_t)(col0 + r) * DD + k0 + sslot * 8;
            const short* blp = BlT + (size_t)(col0 + r) * DD + k0 + sslot * 8;
            *(s16x8*)((char*)Bs_h + byte) = *(const s16x8*)bhp;
            *(s16x8*)((char*)Bs_l + byte) = *(const s16x8*)blp;
        }
        __syncthreads();

        #pragma unroll
        for (int ks = 0; ks < 2; ++ks) {
            s16x8 ah[2], al[2], bh[4], bl[4];
            int g = ks * 4 + (lane >> 4);
            #pragma unroll
            for (int m = 0; m < 2; ++m) {
                int r = wr * 32 + m * 16 + (lane & 15);
                int byte = r * 128 + ((g ^ (r & 7)) << 4);
                ah[m] = *(const s16x8*)((char*)As_h + byte);
                al[m] = *(const s16x8*)((char*)As_l + byte);
            }
            #pragma unroll
            for (int n = 0; n < 4; ++n) {
                int c = wc * 64 + n * 16 + (lane & 15);
                int byte = c * 128 + ((g ^ (c & 7)) << 4);
                bh[n] = *(const s16x8*)((char*)Bs_h + byte);
                bl[n] = *(const s16x8*)((char*)Bs_l + byte);
            }
            #pragma unroll
            for (int m = 0; m < 2; ++m)
                #pragma unroll
                for (int n = 0; n < 4; ++n) {
                    acc[m][n] = __builtin_amdgcn_mfma_f32_16x16x32_bf16(ah[m], bh[n], acc[m][n], 0, 0, 0);
                    acc[m][n] = __builtin_amdgcn_mfma_f32_16x16x32_bf16(ah[m], bl[n], acc[m][n], 0, 0, 0);
                    acc[m][n] = __builtin_amdgcn_mfma_f32_16x16x32_bf16(al[m], bh[n], acc[m][n], 0, 0, 0);
                }
        }
    }

    // fused matvec partials (exact fp32 accumulators), plain stores
    float vsrc[4], vdst[4];
    #pragma unroll
    for (int n = 0; n < 4; ++n) {
        int cg = col0 + wc * 64 + n * 16 + (lane & 15);
        vsrc[n] = a_src[cg];
        vdst[n] = a_dst[cg];
    }
    #pragma unroll
    for (int m = 0; m < 2; ++m) {
        #pragma unroll
        for (int j = 0; j < 4; ++j) {
            float ps = 0.f, pd = 0.f;
            #pragma unroll
            for (int n = 0; n < 4; ++n) {
                float c = acc[m][n][j];
                ps += c * vsrc[n];
                pd += c * vdst[n];
            }
            #pragma unroll
            for (int o = 1; o < 16; o <<= 1) {
                ps += __shfl_xor(ps, o, 64);
                pd += __shfl_xor(pd, o, 64);
            }
            if ((lane & 15) == 0) {
                int rg = row0 + wr * 32 + m * 16 + ((lane >> 4) << 2) + j;
                if (rg < M) {
                    asp[(size_t)(gx * 2 + wc) * NN + rg] = ps;
                    adp[(size_t)(gx * 2 + wc) * NN + rg] = pd;
                }
            }
        }
    }

    // bf16 h output
    #pragma unroll
    for (int m = 0; m < 2; ++m) {
        int rbase = row0 + wr * 32 + m * 16 + ((lane >> 4) << 2);
        #pragma unroll
        for (int n = 0; n < 4; ++n) {
            int cg = col0 + wc * 64 + n * 16 + (lane & 15);
            #pragma unroll
            for (int j = 0; j < 4; ++j) {
                int rg = rbase + j;
                if (rg < M) hb[(size_t)rg * DD + cg] = (short)f2bf_hi(acc[m][n][j]);
            }
        }
    }

    // XCD-partitioned scatter epilogue (layer 1 only)
    if (SCAT && lid < SCHUNKS * NPART) {
        int part = lid & 7;
        int lo = part * PRNG;
        int e0 = (lid >> 3) * SCSZ;
        int e1 = min(e0 + SCSZ, EE);
        for (int i = e0 + tid; i < e1; i += 256) {
            int d = ei[EE + i];
            if ((unsigned)(d - lo) < (unsigned)PRNG) {
                int pos = atomicAdd(&cursor[d], 1);
                csr_src[pos] = ei[i];
            }
        }
    }
}

// ---------------------------------------------------------------------------
// Collapse partial slabs into as_/ad_; write self-loop into last CSR slot.
// ---------------------------------------------------------------------------
__global__ void reduce_kernel(const float* __restrict__ asp, const float* __restrict__ adp,
                              const int* __restrict__ offsets,
                              float* __restrict__ as_, float* __restrict__ ad_,
                              int* __restrict__ csr_src) {
    int i = blockIdx.x * blockDim.x + threadIdx.x;
    if (i < NN) {
        as_[i] = asp[i] + asp[NN + i] + asp[2 * NN + i] + asp[3 * NN + i];
        ad_[i] = adp[i] + adp[NN + i] + adp[2 * NN + i] + adp[3 * NN + i];
        csr_src[offsets[i + 1] - 1] = i;   // self-loop
    }
}

// ---------------------------------------------------------------------------
// Alpha precompute: wave per node; fast path deg<=64. Writes packed
// {src_byte_offset (src*512), alpha} so the aggregate needs no multiply.
// ---------------------------------------------------------------------------
__global__ __launch_bounds__(256) void alpha_kernel(const int* __restrict__ csr_src,
                                                    const int* __restrict__ offsets,
                                                    const float* __restrict__ as_,
                                                    const float* __restrict__ ad_,
                                                    int2* __restrict__ pairs) {
    int tid = threadIdx.x;
    int w = tid >> 6, lane = tid & 63;
    int node = blockIdx.x * 4 + w;
    int off = offsets[node];
    int deg = offsets[node + 1] - off;
    float adn = ad_[node];

    if (deg <= 64) {
        int si = 0; float e = -INFINITY;
        if (lane < deg) {
            si = csr_src[off + lane];
            float t = as_[si] + adn;
            e = (t > 0.f) ? t : 0.2f * t;
        }
        float m = e;
        #pragma unroll
        for (int o = 32; o > 0; o >>= 1) m = fmaxf(m, __shfl_xor(m, o, 64));
        float ex = (lane < deg) ? expf(e - m) : 0.f;
        float s = ex;
        #pragma unroll
        for (int o = 32; o > 0; o >>= 1) s += __shfl_xor(s, o, 64);
        if (lane < deg) {
            int2 p; p.x = si << 9; p.y = __float_as_int(ex / s);
            pairs[off + lane] = p;
        }
        return;
    }

    float m = -INFINITY, s = 0.f;
    for (int cs = 0; cs < deg; cs += 64) {
        int cl = min(64, deg - cs);
        float e = -INFINITY;
        if (lane < cl) {
            int si = csr_src[off + cs + lane];
            float t = as_[si] + adn;
            e = (t > 0.f) ? t : 0.2f * t;
        }
        float cm = e;
        #pragma unroll
        for (int o = 32; o > 0; o >>= 1) cm = fmaxf(cm, __shfl_xor(cm, o, 64));
        float newm = fmaxf(m, cm);
        float ex = (lane < cl) ? expf(e - newm) : 0.f;
        float csum = ex;
        #pragma unroll
        for (int o = 32; o > 0; o >>= 1) csum += __shfl_xor(csum, o, 64);
        s = s * expf(m - newm) + csum;
        m = newm;
    }
    float inv = 1.f / s;
    for (int cs = 0; cs < deg; cs += 64) {
        int cl = min(64, deg - cs);
        if (lane < cl) {
            int si = csr_src[off + cs + lane];
            float t = as_[si] + adn;
            float e = (t > 0.f) ? t : 0.2f * t;
            int2 p; p.x = si << 9; p.y = __float_as_int(expf(e - m) * inv);
            pairs[off + cs + lane] = p;
        }
    }
}

// ---------------------------------------------------------------------------
// Aggregation v4 + byte-offset pairs (round-12/17 proven). Wave per
// (node, 64-feature slice); 8 edge groups x 8 lanes x 16B; pairs prefetched
// one iteration ahead. slice=blockIdx%4 pins each XCD's L2 to one h-slice.
// ---------------------------------------------------------------------------
__global__ __launch_bounds__(256) void aggregate_kernel(const short* __restrict__ hb,
                                                        const int2* __restrict__ pairs,
                                                        const int* __restrict__ offsets,
                                                        const float* __restrict__ bias,
                                                        float* __restrict__ out) {
    int tid = threadIdx.x;
    int w = tid >> 6, lane = tid & 63;
    int b = blockIdx.x;
    int sl = b & 3;
    int node = ((b >> 2) << 2) + w;
    int eg = lane >> 3;          // edge group 0..7
    int fl = lane & 7;           // feature octet
    int f0 = sl * 64 + fl * 8;
    const char* hbF = (const char*)hb + f0 * 2;
    int off = offsets[node];
    int deg = offsets[node + 1] - off;
    const i32x2* pp = (const i32x2*)pairs + off;

    float accA[8], accB[8];
    #pragma unroll
    for (int k = 0; k < 8; ++k) { accA[k] = 0.f; accB[k] = 0.f; }

    int j = 0;
    i32x2 qA, qB;
    if (deg >= 16) { qA = pp[eg]; qB = pp[8 + eg]; }
    for (; j + 32 <= deg; j += 16) {
        i32x2 nA = pp[j + 16 + eg];                  // prefetch next iter
        i32x2 nB = pp[j + 24 + eg];
        fma8o(hbF, qA[0], __int_as_float(qA[1]), accA);
        fma8o(hbF, qB[0], __int_as_float(qB[1]), accB);
        qA = nA; qB = nB;
    }
    if (j + 16 <= deg) {                             // last full iter (pairs in regs)
        fma8o(hbF, qA[0], __int_as_float(qA[1]), accA);
        fma8o(hbF, qB[0], __int_as_float(qB[1]), accB);
        j += 16;
    }
    {   // tail: up to 15 edges, two guarded per-group singles
        if (j + eg < deg) {
            i32x2 p = pp[j + eg];
            fma8o(hbF, p[0], __int_as_float(p[1]), accA);
        }
        if (j + 8 + eg < deg) {
            i32x2 p = pp[j + 8 + eg];
            fma8o(hbF, p[0], __int_as_float(p[1]), accB);
        }
    }

    // merge the 8 edge groups
    f32x4 r0, r1;
    #pragma unroll
    for (int k = 0; k < 8; ++k) {
        float v = accA[k] + accB[k];
        v += __shfl_xor(v, 8, 64);
        v += __shfl_xor(v, 16, 64);
        v += __shfl_xor(v, 32, 64);
        if (k < 4) r0[k] = v; else r1[k - 4] = v;
    }
    if (eg == 0) {
        const f32x4 b0 = *(const f32x4*)(bias + f0);
        const f32x4 b1 = *(const f32x4*)(bias + f0 + 4);
        #pragma unroll
        for (int k = 0; k < 4; ++k) {
            float v0 = r0[k] + b0[k];
            float v1 = r1[k] + b1[k];
            r0[k] = (v0 > 0.f) ? v0 : 0.01f * v0;
            r1[k] = (v1 > 0.f) ? v1 : 0.01f * v1;
        }
        __builtin_nontemporal_store(r0, (f32x4*)(out + (size_t)node * DD + f0));
        __builtin_nontemporal_store(r1, (f32x4*)(out + (size_t)node * DD + f0 + 4));
    }
}

// ---------------------------------------------------------------------------
// Pool + final (BN folded into final)
// ---------------------------------------------------------------------------
#define PSLICE 8
__global__ __launch_bounds__(256) void pool_kernel(const float* __restrict__ h,
                                                   const int* __restrict__ start,
                                                   float* __restrict__ pool) {
    int g = blockIdx.x >> 3, sl = blockIdx.x & (PSLICE - 1);
    int f = threadIdx.x;
    int s0 = start[g], s1 = start[g + 1];
    float acc = 0.f;
    for (int nd = s0 + sl; nd < s1; nd += PSLICE)
        acc += h[(size_t)nd * DD + f];
    if (acc != 0.f || sl == 0) atomicAdd(&pool[g * DD + f], acc);
}

__global__ __launch_bounds__(256) void final_kernel(const float* __restrict__ pool,
                                                    const float* __restrict__ cnt,
                                                    const float* __restrict__ gam,
                                                    const float* __restrict__ bet,
                                                    const float* __restrict__ mean,
                                                    const float* __restrict__ var,
                                                    const float* __restrict__ Wl,
                                                    const float* __restrict__ bl,
                                                    float* __restrict__ out) {
    __shared__ float p_sh[DD];
    int g = blockIdx.x, j = threadIdx.x;
    float cn = cnt[g];
    float scale = gam[j] * rsqrtf(var[j] + BN_EPS);
    p_sh[j] = (cn > 0.f) ? (pool[g * DD + j] / cn - mean[j]) * scale + bet[j] : 0.f;
    __syncthreads();
    float acc = 0.f;
    for (int fi = 0; fi < DD; ++fi)
        acc += p_sh[fi] * Wl[j * DD + fi];
    out[g * DD + j] = acc + bl[j];
}

// ---------------------------------------------------------------------------
extern "C" void kernel_launch(void* const* d_in, const int* in_sizes, int n_in,
                              void* d_out, int out_size, void* d_ws, size_t ws_size,
                              hipStream_t stream) {
    const float* x       = (const float*)d_in[0];
    const int*   ei      = (const int*)d_in[1];
    const int*   batch   = (const int*)d_in[2];
    const float* W1      = (const float*)d_in[3];
    const float* a1_src  = (const float*)d_in[4];
    const float* a1_dst  = (const float*)d_in[5];
    const float* b1      = (const float*)d_in[6];
    const float* W2      = (const float*)d_in[7];
    const float* a2_src  = (const float*)d_in[8];
    const float* a2_dst  = (const float*)d_in[9];
    const float* b2      = (const float*)d_in[10];
    const float* bn_g    = (const float*)d_in[11];
    const float* bn_b    = (const float*)d_in[12];
    const float* bn_m    = (const float*)d_in[13];
    const float* bn_v    = (const float*)d_in[14];
    const float* Wl      = (const float*)d_in[15];
    const float* bl      = (const float*)d_in[16];
    float* out = (float*)d_out;

    char* ws = (char*)d_ws;
    size_t o = 0;
    auto take = [&](size_t bytes) { char* p = ws + o; o += (bytes + 255) & ~(size_t)255; return p; };
    int*   counts  = (int*)  take(NN * 4);
    int*   offsets = (int*)  take((NN + 1) * 4);
    int*   cursor  = (int*)  take(NN * 4);
    int*   csr_src = (int*)  take((size_t)ETOT * 4);
    int2*  pairs   = (int2*) take((size_t)ETOT * 8);
    float* asp     = (float*)take((size_t)4 * NN * 4);
    float* adp     = (float*)take((size_t)4 * NN * 4);
    float* as_     = (float*)take(NN * 4);
    float* ad_     = (float*)take(NN * 4);
    short* hb      = (short*)take((size_t)NN * DD * 2);
    float* bufB    = (float*)take((size_t)NN * DD * 4);
    float* pool    = (float*)take(GG * DD * 4);
    float* cnt     = (float*)take(GG * 4);
    int*   start   = (int*)  take((GG + 1) * 4);
    short* BhT1    = (short*)take((size_t)DD * DD * 2);
    short* BlT1    = (short*)take((size_t)DD * DD * 2);
    short* BhT2    = (short*)take((size_t)DD * DD * 2);
    short* BlT2    = (short*)take((size_t)DD * DD * 2);
    (void)ws_size; (void)in_sizes; (void)n_in; (void)out_size;

    hipMemsetAsync(counts, 0, NN * 4, stream);
    hipMemsetAsync(pool, 0, GG * DD * 4, stream);

    // launch A: hist || convB || prep
    prep_hist_conv_kernel<<<2048, 256, 0, stream>>>(batch, start, cnt, ei, counts,
                                                    W1, W2, BhT1, BlT1, BhT2, BlT2);
    scan_kernel<<<1, 1024, 0, stream>>>(counts, offsets, cursor);

    // ---- layer 1 (GEMM + XCD-partitioned scatter epilogue) ----
    gemm_kernel<true><<<NGEMMB, 256, 0, stream>>>(x, BhT1, BlT1, a1_src, a1_dst,
                                                  hb, asp, adp, NN, ei, cursor, csr_src);
    reduce_kernel<<<(NN + 255) / 256, 256, 0, stream>>>(asp, adp, offsets, as_, ad_, csr_src);
    alpha_kernel<<<NN / 4, 256, 0, stream>>>(csr_src, offsets, as_, ad_, pairs);
    aggregate_kernel<<<NN, 256, 0, stream>>>(hb, pairs, offsets, b1, bufB);

    // ---- layer 2 ----
    gemm_kernel<false><<<NGEMMB, 256, 0, stream>>>(bufB, BhT2, BlT2, a2_src, a2_dst,
                                                   hb, asp, adp, NN, nullptr, nullptr, nullptr);
    reduce_kernel<<<(NN + 255) / 256, 256, 0, stream>>>(asp, adp, offsets, as_, ad_, csr_src);
    alpha_kernel<<<NN / 4, 256, 0, stream>>>(csr_src, offsets, as_, ad_, pairs);
    aggregate_kernel<<<NN, 256, 0, stream>>>(hb, pairs, offsets, b2, bufB);

    // ---- pool + BN + linear ----
    pool_kernel<<<GG * PSLICE, 256, 0, stream>>>(bufB, start, pool);
    final_kernel<<<GG, 256, 0, stream>>>(pool, cnt, bn_g, bn_b, bn_m, bn_v, Wl, bl, out);
}